// Round 5
// baseline (967.626 us; speedup 1.0000x reference)
//
#include <hip/hip_runtime.h>

// out[s][o] = sum_i x[s][i] * dq(w[o][i]); int4 group quant, group=256, scale=max(absmax/7,1e-9)
// x: [16,4096] f32, w: [14336,4096] f32 (235 MB streamed once), out: [16,14336] f32
//
// R5: (1) absmax reduction via DPP on the VALU pipe (was ds_swizzle on the DS
// pipe, which it shared with the x ds_read_b128 stream); scale lands in an
// SGPR via readlane. (2) ping-pong w buffers, FMA->issue load->dequant order:
// no rotate movs, ~1.4-iteration vmcnt cover. (3) 448-thr blocks, 2 blocks/CU
// so barrier stalls of one block overlap the other's compute.

constexpr int O_DIM  = 14336;
constexpr int I_DIM  = 4096;
constexpr int S_DIM  = 16;
constexpr int GS     = 256;           // quant group size
constexpr int NG     = I_DIM / GS;    // 16 groups
constexpr int RPW    = 4;             // rows per wave
constexpr int NWAVE  = 7;             // waves per block (448 thr)
constexpr int RPB    = RPW * NWAVE;   // 28 rows/block -> 512 blocks = 2/CU
constexpr int NTHR   = 64 * NWAVE;
constexpr int PH_I   = 1024;          // i-extent per x staging phase
constexpr int NPH    = I_DIM / PH_I;  // 4 phases
constexpr int GPP    = PH_I / GS;     // 4 groups per phase

// wave64 max-reduce on the VALU pipe: 4x row_shr + bcast15 + bcast31, then
// readlane(63) -> SGPR. Inputs are >=0 so bound_ctrl=true (0-fill) is identity.
__device__ __forceinline__ float wave_max_dpp(float x) {
    int v = __float_as_int(x);
    int t;
    t = __builtin_amdgcn_update_dpp(0, v, 0x111, 0xf, 0xf, true); // row_shr:1
    v = __float_as_int(fmaxf(__int_as_float(v), __int_as_float(t)));
    t = __builtin_amdgcn_update_dpp(0, v, 0x112, 0xf, 0xf, true); // row_shr:2
    v = __float_as_int(fmaxf(__int_as_float(v), __int_as_float(t)));
    t = __builtin_amdgcn_update_dpp(0, v, 0x114, 0xf, 0xf, true); // row_shr:4
    v = __float_as_int(fmaxf(__int_as_float(v), __int_as_float(t)));
    t = __builtin_amdgcn_update_dpp(0, v, 0x118, 0xf, 0xf, true); // row_shr:8
    v = __float_as_int(fmaxf(__int_as_float(v), __int_as_float(t)));
    t = __builtin_amdgcn_update_dpp(0, v, 0x142, 0xf, 0xf, true); // row_bcast:15
    v = __float_as_int(fmaxf(__int_as_float(v), __int_as_float(t)));
    t = __builtin_amdgcn_update_dpp(0, v, 0x143, 0xf, 0xf, true); // row_bcast:31
    v = __float_as_int(fmaxf(__int_as_float(v), __int_as_float(t)));
    return __int_as_float(__builtin_amdgcn_readlane(v, 63));      // wave-uniform
}

__global__ __launch_bounds__(NTHR, 4)
void qlin_kernel(const float* __restrict__ x,
                 const float* __restrict__ w,
                 float* __restrict__ out)
{
    __shared__ float xs[S_DIM][PH_I];   // 64 KB

    const int tid  = threadIdx.x;
    const int lane = tid & 63;
    const int wv   = tid >> 6;          // 0..6
    const int row0 = blockIdx.x * RPB + wv * RPW;

    const float* wp = w + (size_t)row0 * I_DIM + lane * 4;

    float acc[RPW][S_DIM];
#pragma unroll
    for (int r = 0; r < RPW; ++r)
#pragma unroll
        for (int s = 0; s < S_DIM; ++s) acc[r][s] = 0.0f;

    float4 u[RPW], v[RPW];

    auto loadw = [&](int G, float4* dst) {
#pragma unroll
        for (int r = 0; r < RPW; ++r)
            dst[r] = *reinterpret_cast<const float4*>(
                wp + (size_t)r * I_DIM + (size_t)G * GS);
    };
    auto dequant = [&](float4* b) {
#pragma unroll
        for (int r = 0; r < RPW; ++r) {
            float4 t = b[r];
            float m = fmaxf(fmaxf(fabsf(t.x), fabsf(t.y)),
                            fmaxf(fabsf(t.z), fabsf(t.w)));
            m = wave_max_dpp(m);                      // VALU pipe, SGPR result
            float scale = fmaxf(m * (1.0f / 7.0f), 1e-9f);
            float invs  = 1.0f / scale;
            // clamp provably dead: scale >= absmax/7 => |t*invs| <= 7
            b[r].x = rintf(t.x * invs) * scale;
            b[r].y = rintf(t.y * invs) * scale;
            b[r].z = rintf(t.z * invs) * scale;
            b[r].w = rintf(t.w * invs) * scale;
        }
    };
    auto fmagrp = [&](const float4* b, int gloc) {
        const int xb = gloc * GS + lane * 4;
#pragma unroll
        for (int s = 0; s < S_DIM; ++s) {
            float4 xv = *reinterpret_cast<const float4*>(&xs[s][xb]);
#pragma unroll
            for (int r = 0; r < RPW; ++r) {
                acc[r][s] = fmaf(b[r].x, xv.x, acc[r][s]);
                acc[r][s] = fmaf(b[r].y, xv.y, acc[r][s]);
                acc[r][s] = fmaf(b[r].z, xv.z, acc[r][s]);
                acc[r][s] = fmaf(b[r].w, xv.w, acc[r][s]);
            }
        }
    };

    // ---- prologue: groups 0,1 in flight; stage phase 0; dequant group 0 ----
    loadw(0, u);
    loadw(1, v);
    for (int j = tid; j < S_DIM * (PH_I / 4); j += NTHR) {
        const int s  = j >> 8;
        const int i4 = (j & 255) * 4;
        *reinterpret_cast<float4*>(&xs[s][i4]) =
            *reinterpret_cast<const float4*>(&x[(size_t)s * I_DIM + i4]);
    }
    dequant(u);
    __syncthreads();

    for (int p = 0; p < NPH; ++p) {
        if (p) {
            __syncthreads();   // all waves done reading phase p-1
            for (int j = tid; j < S_DIM * (PH_I / 4); j += NTHR) {
                const int s  = j >> 8;
                const int i4 = (j & 255) * 4;
                *reinterpret_cast<float4*>(&xs[s][i4]) =
                    *reinterpret_cast<const float4*>(
                        &x[(size_t)s * I_DIM + p * PH_I + i4]);
            }
            __syncthreads();
        }
#pragma unroll
        for (int g = 0; g < GPP; g += 2) {
            const int G = p * GPP + g;
            fmagrp(u, g);                       // consume dq(G)
            if (G + 2 < NG) loadw(G + 2, u);    // refill freed regs, 1.9-iter cover
            dequant(v);                         // G+1: loads issued ~1.4 iters ago
            fmagrp(v, g + 1);
            if (G + 3 < NG) loadw(G + 3, v);
            if (G + 2 < NG) dequant(u);
        }
    }

    // ---- epilogue: reduce 64 accs across 64 lanes in 63 shuffles ----
    float a[64];
#pragma unroll
    for (int r = 0; r < RPW; ++r)
#pragma unroll
        for (int s = 0; s < S_DIM; ++s) a[(r << 4) | s] = acc[r][s];

#pragma unroll
    for (int m = 32; m >= 1; m >>= 1) {
        const bool hi = (lane & m) != 0;
#pragma unroll
        for (int j = 0; j < m; ++j) {
            float snd  = hi ? a[j] : a[j + m];
            float rcv  = __shfl_xor(snd, m, 64);
            float kept = hi ? a[j + m] : a[j];
            a[j] = kept + rcv;
        }
    }
    {
        const int r = lane >> 4, s = lane & 15;
        out[s * O_DIM + (row0 + r)] = a[0];
    }
}

extern "C" void kernel_launch(void* const* d_in, const int* in_sizes, int n_in,
                              void* d_out, int out_size, void* d_ws, size_t ws_size,
                              hipStream_t stream) {
    const float* x = (const float*)d_in[0];   // 1*16*4096
    const float* w = (const float*)d_in[1];   // 14336*4096
    float* out = (float*)d_out;               // 16*14336
    dim3 grid(O_DIM / RPB);                   // 512 blocks -> 2 per CU
    dim3 block(NTHR);                         // 448 = 7 waves
    qlin_kernel<<<grid, block, 0, stream>>>(x, w, out);
}

// Round 6
// 336.714 us; speedup vs baseline: 2.8737x; 2.8737x over previous
//
#include <hip/hip_runtime.h>

// out[s][o] = sum_i x[s][i] * dq(w[o][i]); int4 group quant, group=256, scale=max(absmax/7,1e-9)
// x: [16,4096] f32, w: [14336,4096] f32 (235 MB streamed once), out: [16,14336] f32
//
// R6 = R4 skeleton (clean registers, x-in-LDS so FMA never waits on w prefetch)
//    + DPP absmax (VALU pipe, frees the DS pipe for the x ds_read_b128 stream)
//    + 448-thr blocks, 512 blocks = 2 blocks/CU (overlap barrier drift)
//    + plain __launch_bounds__(448): R5's (448,4) squeezed VGPRs to 64 ->
//      acc[] spilled to scratch in the K-loop -> 2.4 GB scratch traffic.
//      LDS 64 KB already caps residency at 2 blocks/CU; let VGPRs float.

constexpr int O_DIM  = 14336;
constexpr int I_DIM  = 4096;
constexpr int S_DIM  = 16;
constexpr int GS     = 256;           // quant group size
constexpr int NG     = I_DIM / GS;    // 16 groups
constexpr int RPW    = 4;             // rows per wave
constexpr int NWAVE  = 7;             // waves per block
constexpr int NTHR   = 64 * NWAVE;    // 448
constexpr int RPB    = RPW * NWAVE;   // 28 rows/block -> 512 blocks = 2/CU
constexpr int PH_I   = 1024;          // i-extent per x staging phase
constexpr int NPH    = I_DIM / PH_I;  // 4 phases
constexpr int GPP    = PH_I / GS;     // 4 groups per phase

// wave64 max-reduce on the VALU pipe (validated correct in R5's run):
// 4x row_shr + row_bcast15 + row_bcast31, readlane(63) -> wave-uniform SGPR.
// Inputs >= 0, so bound_ctrl=true zero-fill is identity for max.
__device__ __forceinline__ float wave_max_dpp(float x) {
    int v = __float_as_int(x);
    int t;
    t = __builtin_amdgcn_update_dpp(0, v, 0x111, 0xf, 0xf, true); // row_shr:1
    v = __float_as_int(fmaxf(__int_as_float(v), __int_as_float(t)));
    t = __builtin_amdgcn_update_dpp(0, v, 0x112, 0xf, 0xf, true); // row_shr:2
    v = __float_as_int(fmaxf(__int_as_float(v), __int_as_float(t)));
    t = __builtin_amdgcn_update_dpp(0, v, 0x114, 0xf, 0xf, true); // row_shr:4
    v = __float_as_int(fmaxf(__int_as_float(v), __int_as_float(t)));
    t = __builtin_amdgcn_update_dpp(0, v, 0x118, 0xf, 0xf, true); // row_shr:8
    v = __float_as_int(fmaxf(__int_as_float(v), __int_as_float(t)));
    t = __builtin_amdgcn_update_dpp(0, v, 0x142, 0xf, 0xf, true); // row_bcast:15
    v = __float_as_int(fmaxf(__int_as_float(v), __int_as_float(t)));
    t = __builtin_amdgcn_update_dpp(0, v, 0x143, 0xf, 0xf, true); // row_bcast:31
    v = __float_as_int(fmaxf(__int_as_float(v), __int_as_float(t)));
    return __int_as_float(__builtin_amdgcn_readlane(v, 63));
}

__global__ __launch_bounds__(NTHR)
void qlin_kernel(const float* __restrict__ x,
                 const float* __restrict__ w,
                 float* __restrict__ out)
{
    __shared__ float xs[S_DIM][PH_I];   // 64 KB -> LDS caps at 2 blocks/CU

    const int tid  = threadIdx.x;
    const int lane = tid & 63;
    const int wv   = tid >> 6;          // 0..6
    const int row0 = blockIdx.x * RPB + wv * RPW;

    const float* wp = w + (size_t)row0 * I_DIM + lane * 4;

    float acc[RPW][S_DIM];
#pragma unroll
    for (int r = 0; r < RPW; ++r)
#pragma unroll
        for (int s = 0; s < S_DIM; ++s) acc[r][s] = 0.0f;

    float4 wcur[RPW], wnext[RPW];
#pragma unroll
    for (int r = 0; r < RPW; ++r)
        wcur[r] = *reinterpret_cast<const float4*>(wp + (size_t)r * I_DIM);

    for (int p = 0; p < NPH; ++p) {
        // ---- stage x[:, p*1024 .. +1024) into LDS (4096 float4 / 448 thr) ----
        if (p) __syncthreads();         // all waves done reading phase p-1
        for (int j = tid; j < S_DIM * (PH_I / 4); j += NTHR) {
            const int s  = j >> 8;          // float4-slot / 256-per-row
            const int i4 = (j & 255) * 4;
            *reinterpret_cast<float4*>(&xs[s][i4]) =
                *reinterpret_cast<const float4*>(
                    &x[(size_t)s * I_DIM + p * PH_I + i4]);
        }
        __syncthreads();

        for (int g = 0; g < GPP; ++g) {
            const int G = p * GPP + g;      // global group index

            // next group's w — the only vmem in the steady loop; consumed next
            // iteration, covered by the dequant+FMA below (~900 cyc).
            if (G + 1 < NG) {
#pragma unroll
                for (int r = 0; r < RPW; ++r)
                    wnext[r] = *reinterpret_cast<const float4*>(
                        wp + (size_t)r * I_DIM + (G + 1) * GS);
            }

            // dequant wcur in place; absmax on VALU pipe via DPP
#pragma unroll
            for (int r = 0; r < RPW; ++r) {
                float4 v = wcur[r];
                float m = fmaxf(fmaxf(fabsf(v.x), fabsf(v.y)),
                                fmaxf(fabsf(v.z), fabsf(v.w)));
                m = wave_max_dpp(m);
                float scale = fmaxf(m * (1.0f / 7.0f), 1e-9f);
                float invs  = 1.0f / scale;
                // clamp provably dead: scale >= absmax/7 => |v*invs| <= 7
                wcur[r].x = rintf(v.x * invs) * scale;
                wcur[r].y = rintf(v.y * invs) * scale;
                wcur[r].z = rintf(v.z * invs) * scale;
                wcur[r].w = rintf(v.w * invs) * scale;
            }

            // FMA: x from LDS (lgkmcnt only — never waits on wnext)
            const int xb = g * GS + lane * 4;
#pragma unroll
            for (int s = 0; s < S_DIM; ++s) {
                float4 xv = *reinterpret_cast<const float4*>(&xs[s][xb]);
#pragma unroll
                for (int r = 0; r < RPW; ++r) {
                    acc[r][s] = fmaf(wcur[r].x, xv.x, acc[r][s]);
                    acc[r][s] = fmaf(wcur[r].y, xv.y, acc[r][s]);
                    acc[r][s] = fmaf(wcur[r].z, xv.z, acc[r][s]);
                    acc[r][s] = fmaf(wcur[r].w, xv.w, acc[r][s]);
                }
            }

#pragma unroll
            for (int r = 0; r < RPW; ++r) wcur[r] = wnext[r];
        }
    }

    // ---- epilogue: reduce 64 accs across 64 lanes in 63 shuffles ----
    // value-splitting butterfly; lane l ends with the sum of a[l], l=(r<<4)|s.
    float a[64];
#pragma unroll
    for (int r = 0; r < RPW; ++r)
#pragma unroll
        for (int s = 0; s < S_DIM; ++s) a[(r << 4) | s] = acc[r][s];

#pragma unroll
    for (int m = 32; m >= 1; m >>= 1) {
        const bool hi = (lane & m) != 0;
#pragma unroll
        for (int j = 0; j < m; ++j) {
            float snd  = hi ? a[j] : a[j + m];
            float rcv  = __shfl_xor(snd, m, 64);
            float kept = hi ? a[j + m] : a[j];
            a[j] = kept + rcv;
        }
    }
    {
        const int r = lane >> 4, s = lane & 15;
        out[s * O_DIM + (row0 + r)] = a[0];
    }
}

extern "C" void kernel_launch(void* const* d_in, const int* in_sizes, int n_in,
                              void* d_out, int out_size, void* d_ws, size_t ws_size,
                              hipStream_t stream) {
    const float* x = (const float*)d_in[0];   // 1*16*4096
    const float* w = (const float*)d_in[1];   // 14336*4096
    float* out = (float*)d_out;               // 16*14336
    dim3 grid(O_DIM / RPB);                   // 512 blocks -> 2 per CU
    dim3 block(NTHR);                         // 448 = 7 waves
    qlin_kernel<<<grid, block, 0, stream>>>(x, w, out);
}